// Round 3
// baseline (1635.809 us; speedup 1.0000x reference)
//
#include <hip/hip_runtime.h>

#define N_USER 50000
#define N_ITEM 50000
#define N_NODE 50000
#define N_EDGE 1600000
#define D 64

#define FB_SHIFT 7        // 128 nodes per fine bucket
#define N_FINE 400        // covers 51200 >= 50000 nodes
#define CHUNK 8192        // edges per fine_bin block

// ---------------------------------------------------------------------------
// Kernel 1: dual GEMM. out1 = feat@W1 + b1 (into ws), out2 = feat@W2 + b2
// (self-loop term, straight into d_out). 16 rows per block, W staged in LDS.
// ---------------------------------------------------------------------------
__global__ __launch_bounds__(256) void gemm_dual(
    const float* __restrict__ feat,
    const float* __restrict__ W1, const float* __restrict__ b1, float* __restrict__ out1,
    const float* __restrict__ W2, const float* __restrict__ b2, float* __restrict__ out2,
    int nrows)
{
    __shared__ float sW1[64][64];
    __shared__ float sW2[64][64];
    __shared__ float sF[16][64];
    __shared__ float sb1[64], sb2[64];
    const int tid = threadIdx.x;

    for (int i = tid; i < 4096; i += 256) {
        sW1[i >> 6][i & 63] = W1[i];
        sW2[i >> 6][i & 63] = W2[i];
    }
    if (tid < 64) { sb1[tid] = b1[tid]; sb2[tid] = b2[tid]; }

    const int row0 = blockIdx.x * 16;
    for (int i = tid; i < 1024; i += 256) {
        int r = row0 + (i >> 6);
        sF[i >> 6][i & 63] = (r < nrows) ? feat[(size_t)r * D + (i & 63)] : 0.0f;
    }
    __syncthreads();

    const int c = tid & 63;   // output column
    const int r = tid >> 6;   // handles local rows r, r+4, r+8, r+12
    float a0 = 0.f, a1 = 0.f, a2 = 0.f, a3 = 0.f;
    float l0 = 0.f, l1 = 0.f, l2 = 0.f, l3 = 0.f;
    #pragma unroll
    for (int k = 0; k < 64; ++k) {
        float w1 = sW1[k][c], w2 = sW2[k][c];
        float f0 = sF[r][k], f1 = sF[r + 4][k], f2 = sF[r + 8][k], f3 = sF[r + 12][k];
        a0 += f0 * w1; a1 += f1 * w1; a2 += f2 * w1; a3 += f3 * w1;
        l0 += f0 * w2; l1 += f1 * w2; l2 += f2 * w2; l3 += f3 * w2;
    }
    const float bb1 = sb1[c], bb2 = sb2[c];
    int rr;
    rr = row0 + r;      if (rr < nrows) { out1[(size_t)rr * D + c] = a0 + bb1; out2[(size_t)rr * D + c] = l0 + bb2; }
    rr = row0 + r + 4;  if (rr < nrows) { out1[(size_t)rr * D + c] = a1 + bb1; out2[(size_t)rr * D + c] = l1 + bb2; }
    rr = row0 + r + 8;  if (rr < nrows) { out1[(size_t)rr * D + c] = a2 + bb1; out2[(size_t)rr * D + c] = l2 + bb2; }
    rr = row0 + r + 12; if (rr < nrows) { out1[(size_t)rr * D + c] = a3 + bb1; out2[(size_t)rr * D + c] = l3 + bb2; }
}

// ---------------------------------------------------------------------------
// Kernel 2: fine-bucket histogram (dst>>7) for both etypes, LDS-staged.
// fhist layout: [0,400) = rate (items), [400,800) = rev (users).
// ---------------------------------------------------------------------------
__global__ __launch_bounds__(256) void fhist_kernel(
    const int* __restrict__ dstA, const int* __restrict__ dstB, int* __restrict__ fhist)
{
    __shared__ int h[2 * N_FINE];
    for (int i = threadIdx.x; i < 2 * N_FINE; i += 256) h[i] = 0;
    __syncthreads();
    const int4* dA = (const int4*)dstA;
    const int4* dB = (const int4*)dstB;
    const int n4 = N_EDGE / 4;
    for (int i = blockIdx.x * 256 + threadIdx.x; i < n4; i += gridDim.x * 256) {
        int4 a = dA[i];
        atomicAdd(&h[a.x >> FB_SHIFT], 1);
        atomicAdd(&h[a.y >> FB_SHIFT], 1);
        atomicAdd(&h[a.z >> FB_SHIFT], 1);
        atomicAdd(&h[a.w >> FB_SHIFT], 1);
        int4 b = dB[i];
        atomicAdd(&h[N_FINE + (b.x >> FB_SHIFT)], 1);
        atomicAdd(&h[N_FINE + (b.y >> FB_SHIFT)], 1);
        atomicAdd(&h[N_FINE + (b.z >> FB_SHIFT)], 1);
        atomicAdd(&h[N_FINE + (b.w >> FB_SHIFT)], 1);
    }
    __syncthreads();
    for (int i = threadIdx.x; i < 2 * N_FINE; i += 256) {
        int c = h[i];
        if (c) atomicAdd(&fhist[i], c);
    }
}

// ---------------------------------------------------------------------------
// Kernel 3: one-block exclusive scan of both 400-entry histograms.
// fbase: [2][N_FINE+1]; fcur: [2][N_FINE] working cursors.
// ---------------------------------------------------------------------------
__global__ __launch_bounds__(1024) void fscan_kernel(
    const int* __restrict__ fhist, int* __restrict__ fbase, int* __restrict__ fcur)
{
    __shared__ int s[1024];
    const int half = threadIdx.x >> 9;
    const int j = threadIdx.x & 511;
    int v = (j < N_FINE) ? fhist[half * N_FINE + j] : 0;
    s[threadIdx.x] = v;
    __syncthreads();
    for (int o = 1; o < 512; o <<= 1) {
        int t = (j >= o) ? s[threadIdx.x - o] : 0;
        __syncthreads();
        s[threadIdx.x] += t;
        __syncthreads();
    }
    int excl = s[threadIdx.x] - v;
    if (j < N_FINE) {
        fbase[half * (N_FINE + 1) + j] = excl;
        fcur[half * N_FINE + j] = excl;
    }
    if (j == N_FINE - 1) fbase[half * (N_FINE + 1) + N_FINE] = excl + v;
}

// ---------------------------------------------------------------------------
// Kernel 4: fine binning (multisplit). Each block: count its chunk in LDS,
// reserve one contiguous window per bucket (single global atomic), then
// scatter packed (dst<<16)|src via LDS cursors. Runs per (block,bucket)
// ~20 edges => L2 lines filled by a single block => no write amplification.
// ---------------------------------------------------------------------------
__global__ __launch_bounds__(256) void fine_bin(
    const int* __restrict__ srcA, const int* __restrict__ dstA, unsigned* __restrict__ binA,
    const int* __restrict__ srcB, const int* __restrict__ dstB, unsigned* __restrict__ binB,
    int* __restrict__ fcur)
{
    const int et = blockIdx.y;
    const int* __restrict__ src = et ? srcB : srcA;
    const int* __restrict__ dst = et ? dstB : dstA;
    unsigned* __restrict__ bin  = et ? binB : binA;
    int* __restrict__ fc = fcur + et * N_FINE;

    __shared__ int hist[N_FINE];
    __shared__ int lcur[N_FINE];
    for (int i = threadIdx.x; i < N_FINE; i += 256) hist[i] = 0;
    __syncthreads();

    const int base = blockIdx.x * CHUNK;
    const int n4 = (min(CHUNK, N_EDGE - base)) >> 2;   // N_EDGE % 4 == 0
    const int4* dst4 = (const int4*)(dst + base);
    const int4* src4 = (const int4*)(src + base);

    // pass 1: count
    for (int i = threadIdx.x; i < n4; i += 256) {
        int4 d = dst4[i];
        atomicAdd(&hist[d.x >> FB_SHIFT], 1);
        atomicAdd(&hist[d.y >> FB_SHIFT], 1);
        atomicAdd(&hist[d.z >> FB_SHIFT], 1);
        atomicAdd(&hist[d.w >> FB_SHIFT], 1);
    }
    __syncthreads();
    // reserve contiguous windows
    for (int f = threadIdx.x; f < N_FINE; f += 256) {
        int c = hist[f];
        lcur[f] = c ? atomicAdd(&fc[f], c) : 0;
    }
    __syncthreads();
    // pass 2: scatter
    for (int i = threadIdx.x; i < n4; i += 256) {
        int4 d = dst4[i];
        int4 s = src4[i];
        { int pos = atomicAdd(&lcur[d.x >> FB_SHIFT], 1); bin[pos] = ((unsigned)d.x << 16) | (unsigned)s.x; }
        { int pos = atomicAdd(&lcur[d.y >> FB_SHIFT], 1); bin[pos] = ((unsigned)d.y << 16) | (unsigned)s.y; }
        { int pos = atomicAdd(&lcur[d.z >> FB_SHIFT], 1); bin[pos] = ((unsigned)d.z << 16) | (unsigned)s.z; }
        { int pos = atomicAdd(&lcur[d.w >> FB_SHIFT], 1); bin[pos] = ((unsigned)d.w << 16) | (unsigned)s.w; }
    }
}

// ---------------------------------------------------------------------------
// Kernel 5: fused segment-mean aggregation. One block per fine bucket.
// 128-node accumulator tile in LDS (pad 64->65 to spread banks); per-node
// counts via LDS atomics; epilogue divides and adds into loop term in d_out.
// ---------------------------------------------------------------------------
__global__ __launch_bounds__(256) void aggregate_fused(
    const float4* __restrict__ WhI,   // Wh_rate: messages to items
    const float4* __restrict__ WhU,   // Wh_rev : messages to users
    const unsigned* __restrict__ binI, const unsigned* __restrict__ binU,
    const int* __restrict__ fbase, float4* __restrict__ out)
{
    const int et = blockIdx.y;        // 0: items (rate), 1: users (rev)
    const unsigned* __restrict__ bin = et ? binU : binI;
    const float4* __restrict__ Wh    = et ? WhU : WhI;
    const int* fb = fbase + et * (N_FINE + 1);
    const int f = blockIdx.x;
    const int start = fb[f], end = fb[f + 1];
    if (start == end) return;

    __shared__ float acc[128][65];
    __shared__ int cnt[128];
    for (int i = threadIdx.x; i < 128 * 65; i += 256) (&acc[0][0])[i] = 0.0f;
    if (threadIdx.x < 128) cnt[threadIdx.x] = 0;
    __syncthreads();

    const int nodebase = f << FB_SHIFT;
    const int grp = threadIdx.x >> 4;
    const int lane = threadIdx.x & 15;
    const int c0 = lane * 4;

    for (int e = start + grp; e < end; e += 16) {
        unsigned p = bin[e];
        int ld = (int)(p >> 16) - nodebase;
        int s  = (int)(p & 0xFFFFu);
        float4 v = Wh[(size_t)s * 16 + lane];
        atomicAdd(&acc[ld][c0 + 0], v.x);
        atomicAdd(&acc[ld][c0 + 1], v.y);
        atomicAdd(&acc[ld][c0 + 2], v.z);
        atomicAdd(&acc[ld][c0 + 3], v.w);
        if (lane == 0) atomicAdd(&cnt[ld], 1);
    }
    __syncthreads();

    const size_t outbase = et ? 0 : (size_t)N_USER * 16;
    for (int i = threadIdx.x; i < 2048; i += 256) {
        int nd = i >> 4, ln = i & 15;
        int g = nodebase + nd;
        if (g < N_NODE) {
            int c = cnt[nd];
            if (c > 0) {
                float inv = 1.0f / (float)c;
                size_t oi = outbase + (size_t)g * 16 + ln;
                float4 o = out[oi];
                o.x += acc[nd][ln * 4 + 0] * inv;
                o.y += acc[nd][ln * 4 + 1] * inv;
                o.z += acc[nd][ln * 4 + 2] * inv;
                o.w += acc[nd][ln * 4 + 3] * inv;
                out[oi] = o;
            }
        }
    }
}

// ---------------------------------------------------------------------------
extern "C" void kernel_launch(void* const* d_in, const int* in_sizes, int n_in,
                              void* d_out, int out_size, void* d_ws, size_t ws_size,
                              hipStream_t stream)
{
    const float* user_feat = (const float*)d_in[0];
    const float* item_feat = (const float*)d_in[1];
    const int*   rate_src  = (const int*)d_in[2];
    const int*   rate_dst  = (const int*)d_in[3];
    const int*   rev_src   = (const int*)d_in[4];
    const int*   rev_dst   = (const int*)d_in[5];
    const float* W_rate    = (const float*)d_in[6];
    const float* b_rate    = (const float*)d_in[7];
    const float* W_rev     = (const float*)d_in[8];
    const float* b_rev     = (const float*)d_in[9];
    const float* loop_w    = (const float*)d_in[10];
    const float* h_bias    = (const float*)d_in[11];
    float* out = (float*)d_out;

    // workspace layout (~38.5 MB)
    char* p = (char*)d_ws;
    float* Wh_rate = (float*)p; p += (size_t)N_USER * D * sizeof(float);   // msgs to items
    float* Wh_rev  = (float*)p; p += (size_t)N_ITEM * D * sizeof(float);   // msgs to users
    unsigned* binI = (unsigned*)p; p += (size_t)N_EDGE * sizeof(unsigned); // rate edges, fine-binned
    unsigned* binU = (unsigned*)p; p += (size_t)N_EDGE * sizeof(unsigned); // rev edges, fine-binned
    int* fhist = (int*)p; p += (size_t)(2 * N_FINE) * sizeof(int);
    int* fbase = (int*)p; p += (size_t)(2 * (N_FINE + 1)) * sizeof(int);
    int* fcur  = (int*)p; p += (size_t)(2 * N_FINE) * sizeof(int);
    (void)ws_size;

    // zero the fine histograms only (3.2 KB)
    hipMemsetAsync(fhist, 0, (size_t)(2 * N_FINE) * sizeof(int), stream);

    // 1) dual GEMMs: Wh_etype into ws, loop term + bias into d_out
    gemm_dual<<<(N_USER + 15) / 16, 256, 0, stream>>>(
        user_feat, W_rate, b_rate, Wh_rate, loop_w, h_bias, out, N_USER);
    gemm_dual<<<(N_ITEM + 15) / 16, 256, 0, stream>>>(
        item_feat, W_rev, b_rev, Wh_rev, loop_w, h_bias, out + (size_t)N_USER * D, N_ITEM);

    // 2) fine-bucket histograms (both etypes)
    fhist_kernel<<<256, 256, 0, stream>>>(rate_dst, rev_dst, fhist);

    // 3) exclusive scan -> bucket bases + cursors
    fscan_kernel<<<1, 1024, 0, stream>>>(fhist, fbase, fcur);

    // 4) fine binning (multisplit)
    fine_bin<<<dim3((N_EDGE + CHUNK - 1) / CHUNK, 2), 256, 0, stream>>>(
        rate_src, rate_dst, binI,
        rev_src,  rev_dst,  binU, fcur);

    // 5) fused segment-mean + loop-term add
    aggregate_fused<<<dim3(N_FINE, 2), 256, 0, stream>>>(
        (const float4*)Wh_rate, (const float4*)Wh_rev, binI, binU, fbase,
        (float4*)out);

    (void)in_sizes; (void)n_in; (void)out_size;
}

// Round 4
// 426.825 us; speedup vs baseline: 3.8325x; 3.8325x over previous
//
#include <hip/hip_runtime.h>

#define N_USER 50000
#define N_ITEM 50000
#define N_NODE 50000
#define N_EDGE 1600000
#define D 64

#define FB_SHIFT 7        // 128 nodes per fine bucket
#define N_FINE 400        // covers 51200 >= 50000 nodes
#define CHUNK 8192        // edges per fine_bin block

// ---------------------------------------------------------------------------
// Kernel 1: dual GEMM. out1 = feat@W1 + b1 (into ws), out2 = feat@W2 + b2
// (self-loop term, straight into d_out). 16 rows per block, W staged in LDS.
// ---------------------------------------------------------------------------
__global__ __launch_bounds__(256) void gemm_dual(
    const float* __restrict__ feat,
    const float* __restrict__ W1, const float* __restrict__ b1, float* __restrict__ out1,
    const float* __restrict__ W2, const float* __restrict__ b2, float* __restrict__ out2,
    int nrows)
{
    __shared__ float sW1[64][64];
    __shared__ float sW2[64][64];
    __shared__ float sF[16][64];
    __shared__ float sb1[64], sb2[64];
    const int tid = threadIdx.x;

    for (int i = tid; i < 4096; i += 256) {
        sW1[i >> 6][i & 63] = W1[i];
        sW2[i >> 6][i & 63] = W2[i];
    }
    if (tid < 64) { sb1[tid] = b1[tid]; sb2[tid] = b2[tid]; }

    const int row0 = blockIdx.x * 16;
    for (int i = tid; i < 1024; i += 256) {
        int r = row0 + (i >> 6);
        sF[i >> 6][i & 63] = (r < nrows) ? feat[(size_t)r * D + (i & 63)] : 0.0f;
    }
    __syncthreads();

    const int c = tid & 63;   // output column
    const int r = tid >> 6;   // handles local rows r, r+4, r+8, r+12
    float a0 = 0.f, a1 = 0.f, a2 = 0.f, a3 = 0.f;
    float l0 = 0.f, l1 = 0.f, l2 = 0.f, l3 = 0.f;
    #pragma unroll
    for (int k = 0; k < 64; ++k) {
        float w1 = sW1[k][c], w2 = sW2[k][c];
        float f0 = sF[r][k], f1 = sF[r + 4][k], f2 = sF[r + 8][k], f3 = sF[r + 12][k];
        a0 += f0 * w1; a1 += f1 * w1; a2 += f2 * w1; a3 += f3 * w1;
        l0 += f0 * w2; l1 += f1 * w2; l2 += f2 * w2; l3 += f3 * w2;
    }
    const float bb1 = sb1[c], bb2 = sb2[c];
    int rr;
    rr = row0 + r;      if (rr < nrows) { out1[(size_t)rr * D + c] = a0 + bb1; out2[(size_t)rr * D + c] = l0 + bb2; }
    rr = row0 + r + 4;  if (rr < nrows) { out1[(size_t)rr * D + c] = a1 + bb1; out2[(size_t)rr * D + c] = l1 + bb2; }
    rr = row0 + r + 8;  if (rr < nrows) { out1[(size_t)rr * D + c] = a2 + bb1; out2[(size_t)rr * D + c] = l2 + bb2; }
    rr = row0 + r + 12; if (rr < nrows) { out1[(size_t)rr * D + c] = a3 + bb1; out2[(size_t)rr * D + c] = l3 + bb2; }
}

// ---------------------------------------------------------------------------
// Kernel 2: fine-bucket histogram (dst>>7) for both etypes, LDS-staged.
// ---------------------------------------------------------------------------
__global__ __launch_bounds__(256) void fhist_kernel(
    const int* __restrict__ dstA, const int* __restrict__ dstB, int* __restrict__ fhist)
{
    __shared__ int h[2 * N_FINE];
    for (int i = threadIdx.x; i < 2 * N_FINE; i += 256) h[i] = 0;
    __syncthreads();
    const int4* dA = (const int4*)dstA;
    const int4* dB = (const int4*)dstB;
    const int n4 = N_EDGE / 4;
    for (int i = blockIdx.x * 256 + threadIdx.x; i < n4; i += gridDim.x * 256) {
        int4 a = dA[i];
        atomicAdd(&h[a.x >> FB_SHIFT], 1);
        atomicAdd(&h[a.y >> FB_SHIFT], 1);
        atomicAdd(&h[a.z >> FB_SHIFT], 1);
        atomicAdd(&h[a.w >> FB_SHIFT], 1);
        int4 b = dB[i];
        atomicAdd(&h[N_FINE + (b.x >> FB_SHIFT)], 1);
        atomicAdd(&h[N_FINE + (b.y >> FB_SHIFT)], 1);
        atomicAdd(&h[N_FINE + (b.z >> FB_SHIFT)], 1);
        atomicAdd(&h[N_FINE + (b.w >> FB_SHIFT)], 1);
    }
    __syncthreads();
    for (int i = threadIdx.x; i < 2 * N_FINE; i += 256) {
        int c = h[i];
        if (c) atomicAdd(&fhist[i], c);
    }
}

// ---------------------------------------------------------------------------
// Kernel 3: one-block exclusive scan of both 400-entry histograms.
// ---------------------------------------------------------------------------
__global__ __launch_bounds__(1024) void fscan_kernel(
    const int* __restrict__ fhist, int* __restrict__ fbase, int* __restrict__ fcur)
{
    __shared__ int s[1024];
    const int half = threadIdx.x >> 9;
    const int j = threadIdx.x & 511;
    int v = (j < N_FINE) ? fhist[half * N_FINE + j] : 0;
    s[threadIdx.x] = v;
    __syncthreads();
    for (int o = 1; o < 512; o <<= 1) {
        int t = (j >= o) ? s[threadIdx.x - o] : 0;
        __syncthreads();
        s[threadIdx.x] += t;
        __syncthreads();
    }
    int excl = s[threadIdx.x] - v;
    if (j < N_FINE) {
        fbase[half * (N_FINE + 1) + j] = excl;
        fcur[half * N_FINE + j] = excl;
    }
    if (j == N_FINE - 1) fbase[half * (N_FINE + 1) + N_FINE] = excl + v;
}

// ---------------------------------------------------------------------------
// Kernel 4: fine binning (multisplit). Each block: count its chunk in LDS,
// reserve one contiguous window per bucket (single global atomic), then
// scatter packed (dst<<16)|src via LDS cursors.
// ---------------------------------------------------------------------------
__global__ __launch_bounds__(256) void fine_bin(
    const int* __restrict__ srcA, const int* __restrict__ dstA, unsigned* __restrict__ binA,
    const int* __restrict__ srcB, const int* __restrict__ dstB, unsigned* __restrict__ binB,
    int* __restrict__ fcur)
{
    const int et = blockIdx.y;
    const int* __restrict__ src = et ? srcB : srcA;
    const int* __restrict__ dst = et ? dstB : dstA;
    unsigned* __restrict__ bin  = et ? binB : binA;
    int* __restrict__ fc = fcur + et * N_FINE;

    __shared__ int hist[N_FINE];
    __shared__ int lcur[N_FINE];
    for (int i = threadIdx.x; i < N_FINE; i += 256) hist[i] = 0;
    __syncthreads();

    const int base = blockIdx.x * CHUNK;
    const int n4 = (min(CHUNK, N_EDGE - base)) >> 2;   // N_EDGE % 4 == 0
    const int4* dst4 = (const int4*)(dst + base);
    const int4* src4 = (const int4*)(src + base);

    // pass 1: count
    for (int i = threadIdx.x; i < n4; i += 256) {
        int4 d = dst4[i];
        atomicAdd(&hist[d.x >> FB_SHIFT], 1);
        atomicAdd(&hist[d.y >> FB_SHIFT], 1);
        atomicAdd(&hist[d.z >> FB_SHIFT], 1);
        atomicAdd(&hist[d.w >> FB_SHIFT], 1);
    }
    __syncthreads();
    // reserve contiguous windows
    for (int f = threadIdx.x; f < N_FINE; f += 256) {
        int c = hist[f];
        lcur[f] = c ? atomicAdd(&fc[f], c) : 0;
    }
    __syncthreads();
    // pass 2: scatter
    for (int i = threadIdx.x; i < n4; i += 256) {
        int4 d = dst4[i];
        int4 s = src4[i];
        { int pos = atomicAdd(&lcur[d.x >> FB_SHIFT], 1); bin[pos] = ((unsigned)d.x << 16) | (unsigned)s.x; }
        { int pos = atomicAdd(&lcur[d.y >> FB_SHIFT], 1); bin[pos] = ((unsigned)d.y << 16) | (unsigned)s.y; }
        { int pos = atomicAdd(&lcur[d.z >> FB_SHIFT], 1); bin[pos] = ((unsigned)d.z << 16) | (unsigned)s.z; }
        { int pos = atomicAdd(&lcur[d.w >> FB_SHIFT], 1); bin[pos] = ((unsigned)d.w << 16) | (unsigned)s.w; }
    }
}

// ---------------------------------------------------------------------------
// Kernel 5: per-bucket counting sort. One block per fine bucket (128 nodes,
// ~4K edges). Counts per node in LDS, scans, writes per-node `off` directly,
// then scatters src into the block-private 16KB srt window (full-line
// combining in whichever L2 owns this block -> no write amplification).
// ---------------------------------------------------------------------------
__global__ __launch_bounds__(256) void bucket_sort(
    const unsigned* __restrict__ binI, int* __restrict__ srtI, int* __restrict__ offI,
    const unsigned* __restrict__ binU, int* __restrict__ srtU, int* __restrict__ offU,
    const int* __restrict__ fbase)
{
    const int et = blockIdx.y;
    const unsigned* __restrict__ bin = et ? binU : binI;
    int* __restrict__ srt = et ? srtU : srtI;
    int* __restrict__ off = et ? offU : offI;
    const int* fb = fbase + et * (N_FINE + 1);
    const int f = blockIdx.x;
    const int start = fb[f], end = fb[f + 1];
    const int nodebase = f << FB_SHIFT;

    __shared__ int cnt[128];
    __shared__ int sc[128];
    __shared__ int pos[128];
    if (threadIdx.x < 128) cnt[threadIdx.x] = 0;
    __syncthreads();

    // pass 1: per-node counts
    for (int e = start + threadIdx.x; e < end; e += 256) {
        int ld = (int)(bin[e] >> 16) - nodebase;
        atomicAdd(&cnt[ld], 1);
    }
    __syncthreads();

    // inclusive scan over 128 counters
    if (threadIdx.x < 128) sc[threadIdx.x] = cnt[threadIdx.x];
    __syncthreads();
    for (int o = 1; o < 128; o <<= 1) {
        int t = 0;
        if (threadIdx.x < 128 && threadIdx.x >= o) t = sc[threadIdx.x - o];
        __syncthreads();
        if (threadIdx.x < 128) sc[threadIdx.x] += t;
        __syncthreads();
    }
    if (threadIdx.x < 128) {
        int base = start + sc[threadIdx.x] - cnt[threadIdx.x];   // exclusive
        pos[threadIdx.x] = base;
        int node = nodebase + threadIdx.x;
        if (node < N_NODE) off[node] = base;
    }
    if (threadIdx.x == 0 && f == N_FINE - 1) off[N_NODE] = N_EDGE;
    __syncthreads();

    // pass 2: scatter into private window
    for (int e = start + threadIdx.x; e < end; e += 256) {
        unsigned p = bin[e];
        int ld = (int)(p >> 16) - nodebase;
        int q = atomicAdd(&pos[ld], 1);
        srt[q] = (int)(p & 0xFFFFu);
    }
}

// ---------------------------------------------------------------------------
// Kernel 6: segment mean + add into loop term already in d_out.
// 16 lanes per dst node, float4 per lane, unroll-2 for MLP.
// ---------------------------------------------------------------------------
__global__ __launch_bounds__(256) void aggregate_kernel(
    const float4* __restrict__ WhU,  // Wh_rev  (item-sourced msgs -> users)
    const float4* __restrict__ WhI,  // Wh_rate (user-sourced msgs -> items)
    const int* __restrict__ offU, const int* __restrict__ srtU,
    const int* __restrict__ offI, const int* __restrict__ srtI,
    float4* __restrict__ out)
{
    int g = blockIdx.x * 16 + (threadIdx.x >> 4);
    if (g >= N_USER + N_ITEM) return;
    const int lane = threadIdx.x & 15;

    const bool isUser = (g < N_USER);
    const int d = isUser ? g : g - N_USER;
    const float4* __restrict__ Wh = isUser ? WhU : WhI;
    const int* __restrict__ off   = isUser ? offU : offI;
    const int* __restrict__ srt   = isUser ? srtU : srtI;

    const int start = off[d];
    const int end   = off[d + 1];

    float4 a0 = make_float4(0.f, 0.f, 0.f, 0.f);
    float4 a1 = make_float4(0.f, 0.f, 0.f, 0.f);
    int e = start;
    for (; e + 2 <= end; e += 2) {
        int s0 = srt[e], s1 = srt[e + 1];
        float4 v0 = Wh[(size_t)s0 * 16 + lane];
        float4 v1 = Wh[(size_t)s1 * 16 + lane];
        a0.x += v0.x; a0.y += v0.y; a0.z += v0.z; a0.w += v0.w;
        a1.x += v1.x; a1.y += v1.y; a1.z += v1.z; a1.w += v1.w;
    }
    if (e < end) {
        int s0 = srt[e];
        float4 v0 = Wh[(size_t)s0 * 16 + lane];
        a0.x += v0.x; a0.y += v0.y; a0.z += v0.z; a0.w += v0.w;
    }
    a0.x += a1.x; a0.y += a1.y; a0.z += a1.z; a0.w += a1.w;

    const int cnt = end - start;
    const float inv = 1.0f / (float)(cnt > 0 ? cnt : 1);

    float4* o = out + (size_t)g * 16 + lane;
    float4 curv = *o;
    curv.x += a0.x * inv; curv.y += a0.y * inv;
    curv.z += a0.z * inv; curv.w += a0.w * inv;
    *o = curv;
}

// ---------------------------------------------------------------------------
extern "C" void kernel_launch(void* const* d_in, const int* in_sizes, int n_in,
                              void* d_out, int out_size, void* d_ws, size_t ws_size,
                              hipStream_t stream)
{
    const float* user_feat = (const float*)d_in[0];
    const float* item_feat = (const float*)d_in[1];
    const int*   rate_src  = (const int*)d_in[2];
    const int*   rate_dst  = (const int*)d_in[3];
    const int*   rev_src   = (const int*)d_in[4];
    const int*   rev_dst   = (const int*)d_in[5];
    const float* W_rate    = (const float*)d_in[6];
    const float* b_rate    = (const float*)d_in[7];
    const float* W_rev     = (const float*)d_in[8];
    const float* b_rev     = (const float*)d_in[9];
    const float* loop_w    = (const float*)d_in[10];
    const float* h_bias    = (const float*)d_in[11];
    float* out = (float*)d_out;

    // workspace layout (~52 MB)
    char* p = (char*)d_ws;
    float* Wh_rate = (float*)p; p += (size_t)N_USER * D * sizeof(float);   // msgs to items
    float* Wh_rev  = (float*)p; p += (size_t)N_ITEM * D * sizeof(float);   // msgs to users
    unsigned* binI = (unsigned*)p; p += (size_t)N_EDGE * sizeof(unsigned);
    unsigned* binU = (unsigned*)p; p += (size_t)N_EDGE * sizeof(unsigned);
    int* srtI = (int*)p; p += (size_t)N_EDGE * sizeof(int);
    int* srtU = (int*)p; p += (size_t)N_EDGE * sizeof(int);
    int* offI = (int*)p; p += (size_t)(N_NODE + 1) * sizeof(int);
    int* offU = (int*)p; p += (size_t)(N_NODE + 1) * sizeof(int);
    int* fhist = (int*)p; p += (size_t)(2 * N_FINE) * sizeof(int);
    int* fbase = (int*)p; p += (size_t)(2 * (N_FINE + 1)) * sizeof(int);
    int* fcur  = (int*)p; p += (size_t)(2 * N_FINE) * sizeof(int);
    (void)ws_size;

    // zero the fine histograms only (3.2 KB)
    hipMemsetAsync(fhist, 0, (size_t)(2 * N_FINE) * sizeof(int), stream);

    // 1) dual GEMMs: Wh_etype into ws, loop term + bias into d_out
    gemm_dual<<<(N_USER + 15) / 16, 256, 0, stream>>>(
        user_feat, W_rate, b_rate, Wh_rate, loop_w, h_bias, out, N_USER);
    gemm_dual<<<(N_ITEM + 15) / 16, 256, 0, stream>>>(
        item_feat, W_rev, b_rev, Wh_rev, loop_w, h_bias, out + (size_t)N_USER * D, N_ITEM);

    // 2) fine-bucket histograms
    fhist_kernel<<<256, 256, 0, stream>>>(rate_dst, rev_dst, fhist);

    // 3) exclusive scan -> bucket bases + cursors
    fscan_kernel<<<1, 1024, 0, stream>>>(fhist, fbase, fcur);

    // 4) fine binning (multisplit)
    fine_bin<<<dim3((N_EDGE + CHUNK - 1) / CHUNK, 2), 256, 0, stream>>>(
        rate_src, rate_dst, binI,
        rev_src,  rev_dst,  binU, fcur);

    // 5) per-bucket counting sort -> srt + per-node off
    bucket_sort<<<dim3(N_FINE, 2), 256, 0, stream>>>(
        binI, srtI, offI,
        binU, srtU, offU, fbase);

    // 6) segment mean + loop-term add
    aggregate_kernel<<<(N_USER + N_ITEM + 15) / 16, 256, 0, stream>>>(
        (const float4*)Wh_rev, (const float4*)Wh_rate, offU, srtU, offI, srtI,
        (float4*)out);

    (void)in_sizes; (void)n_in; (void)out_size;
}